// Round 8
// baseline (1174.007 us; speedup 1.0000x reference)
//
#include <hip/hip_runtime.h>
#include <stdint.h>
#include <stddef.h>

#define D_MODEL 2048
#define D_INNER 4096

typedef float f32x4 __attribute__((ext_vector_type(4)));
typedef short short8 __attribute__((ext_vector_type(8)));
typedef __bf16 bf16x8 __attribute__((ext_vector_type(8)));

static __device__ __forceinline__ unsigned short f32_to_bf16(float f){
  unsigned int u = __builtin_bit_cast(unsigned int, f);
  u += 0x7FFFu + ((u >> 16) & 1u);
  return (unsigned short)(u >> 16);
}

static __device__ __forceinline__ f32x4 mfma_bf16(short8 a, short8 b, f32x4 c){
  return __builtin_amdgcn_mfma_f32_16x16x32_bf16(
      __builtin_bit_cast(bf16x8, a), __builtin_bit_cast(bf16x8, b), c, 0, 0, 0);
}

static __device__ __forceinline__ void gload_lds16(const void* g, void* l){
  __builtin_amdgcn_global_load_lds(
      (const __attribute__((address_space(1))) void*)g,
      (__attribute__((address_space(3))) void*)l, 16, 0, 0);
}

// compiler-fence + barrier: empty asm is codegen-free but stops the compiler
// moving memory ops across; the barrier itself emits no waitcnt drain.
#define BARF() do { asm volatile("" ::: "memory"); \
                    __builtin_amdgcn_s_barrier();  \
                    asm volatile("" ::: "memory"); } while(0)

// coef[c] = conv_w[c,3] + softplus(dt[c]) * sum_n(B[c,n]*C[c,n]) + Dp[c]
__global__ void prep_coef_k(const float* __restrict__ conv_w, const float* __restrict__ Bm,
                            const float* __restrict__ Cm, const float* __restrict__ Dp,
                            const float* __restrict__ dt, float* __restrict__ coef){
  int c = blockIdx.x * 256 + threadIdx.x;
  if (c >= D_INNER) return;
  float d = dt[c];
  float sp = (d > 20.f) ? d : log1pf(__expf(d));
  float bc = 0.f;
  #pragma unroll
  for (int n = 0; n < 16; n++) bc += Bm[c*16+n] * Cm[c*16+n];
  coef[c] = conv_w[c*4+3] + sp * bc + Dp[c];
}

// in f32 [K][N] -> out bf16 [N][K]
__global__ void transpose_cvt_k(const float* __restrict__ in, unsigned short* __restrict__ outT,
                                int K, int N){
  __shared__ float t[32][33];
  int n0 = blockIdx.x * 32, k0 = blockIdx.y * 32;
  int tx = threadIdx.x, ty = threadIdx.y;
  #pragma unroll
  for (int i = 0; i < 4; i++)
    t[ty + 8*i][tx] = in[(size_t)(k0 + ty + 8*i) * N + n0 + tx];
  __syncthreads();
  #pragma unroll
  for (int i = 0; i < 4; i++)
    outT[(size_t)(n0 + ty + 8*i) * K + k0 + tx] = f32_to_bf16(t[tx][ty + 8*i]);
}

// x f32 -> bf16, vectorized
__global__ void cvt_x_k(const float4* __restrict__ x, ushort4* __restrict__ xb, int n4){
  int stride = gridDim.x * blockDim.x;
  for (int i = blockIdx.x * blockDim.x + threadIdx.x; i < n4; i += stride){
    float4 v = x[i];
    ushort4 o;
    o.x = f32_to_bf16(v.x); o.y = f32_to_bf16(v.y);
    o.z = f32_to_bf16(v.z); o.w = f32_to_bf16(v.w);
    xb[i] = o;
  }
}

// ---------------------------------------------------------------------------
// 256x256 GEMM, 4 merged phases/iter, UNPINNED (round-8 change).
// C[M,N] = A[M,K]*Bt[N,K]^T, bf16 in, f32 accum.
// 512 thr = 8 waves (2M x 4N); per-wave 128x64 C. BK=64 in 2 K-halves.
// LDS: [slot:2][mat:2][ks:2][256 rows][32 k] bf16 = 128 KiB.
// Swizzle: 16B-chunk c' = c ^ ((row>>1)&3) -> conflict-free ds_read_b128.
// Block order: XCD-contiguous chunks, nb-fast (A re-reads L2-hit; B in L3).
// ROUND-8: the explicit lgkmcnt(0)+"memory"+sched_barrier pins are REMOVED.
// Rounds 2-7 all pinned every phase's 12 ds_reads to complete before any
// MFMA -> burst-serialized LDS(4.6k cyc) + MFMA(5k cyc) ~ measured 12.1k
// cyc/iter at MfmaUtil 41%. Data-deps give per-MFMA fine-grained lgkm waits
// (m97 r109: compiler emits lgkmcnt(4/3/1/0) near-optimally); rule #18 does
// not apply (no inline-asm ds_reads). WAR safety: reads are memory ops, kept
// issued-before-barrier by the codegen-free ""::"memory" fence in BARF;
// LDS services cross-wave ops in arrival order (template assumption).
// vmcnt(4) at phases 2,4 (with clobber - the cross-wave publish fence)
// unchanged: lands exactly the regions the next 2 phases read.
// Epilogue: acc -> LDS (after vmcnt(0)) -> full-line dwordx4 stores.
// All epilogue acc indices compile-time (rule #20: runtime idx -> scratch).
// ---------------------------------------------------------------------------
template<int EPI>
__global__ __launch_bounds__(512, 2) void gemm8_k(
    const unsigned short* __restrict__ A,   // [M][K] bf16
    const unsigned short* __restrict__ Bt,  // [N][K] bf16
    int M, int N, int K,
    const float* __restrict__ bias,
    const float* __restrict__ coef,
    const float* __restrict__ convb,
    unsigned short* __restrict__ gate,
    float* __restrict__ out)
{
  __shared__ __align__(16) unsigned short smem[65536];   // 128 KiB
  char* ldsc = (char*)smem;

  const int tid = threadIdx.x;
  const int wid = tid >> 6, lane = tid & 63;
  const int wr = wid >> 2, wc = wid & 3;          // 2x4 wave grid
  const int l15 = lane & 15, lg = lane >> 4;

  const int nbx = N >> 8;
  const int cpx = gridDim.x >> 3;
  const int bid = blockIdx.x;
  const int swz = (bid & 7) * cpx + (bid >> 3);   // XCD-contiguous (nwg%8==0)
  const int mb = swz / nbx, nb = swz % nbx;       // nb-fast within XCD chunk
  const int m0 = mb << 8, n0 = nb << 8;

  // compute-side ds_read offsets (bytes within a 16 KiB region)
  const int cswz = lg ^ ((l15 >> 1) & 3);
  const int aoff = (wr*128 + l15)*64 + cswz*16;
  const int boff = (wc*64  + l15)*64 + cswz*16;

  // stage-side mapping: 2 instrs/thread, linear LDS dest, pre-swizzled source
  const int s0 = wid*128 + lane;
  const int s1 = s0 + 64;
  const int r0 = s0 >> 2, r1 = s1 >> 2;
  const int c0 = (s0 & 3) ^ ((r0 >> 1) & 3);
  const int c1 = (s1 & 3) ^ ((r1 >> 1) & 3);
  const unsigned short* pA0 = A  + (size_t)(m0 + r0)*K + c0*8;
  const unsigned short* pA1 = A  + (size_t)(m0 + r1)*K + c1*8;
  const unsigned short* pB0 = Bt + (size_t)(n0 + r0)*K + c0*8;
  const unsigned short* pB1 = Bt + (size_t)(n0 + r1)*K + c1*8;

  const int ntile = K >> 6;

#define STAGE_(ST, SKS, SMAT) do {                                          \
    int st_ = (ST); if (st_ > ntile-1) st_ = ntile-1;                       \
    const int ktks_ = st_*64 + (SKS)*32;                                    \
    unsigned short* reg_ = smem + ((st_ & 1) << 15) + ((SMAT) << 14) + ((SKS) << 13); \
    if ((SMAT) == 0) {                                                      \
      gload_lds16(pA0 + ktks_, reg_ + s0*8);                                \
      gload_lds16(pA1 + ktks_, reg_ + s1*8);                                \
    } else {                                                                \
      gload_lds16(pB0 + ktks_, reg_ + s0*8);                                \
      gload_lds16(pB1 + ktks_, reg_ + s1*8);                                \
    }                                                                       \
  } while(0)

  f32x4 acc[8][4];
  #pragma unroll
  for (int i = 0; i < 8; i++)
    #pragma unroll
    for (int j = 0; j < 4; j++)
      #pragma unroll
      for (int r = 0; r < 4; r++) acc[i][j][r] = 0.f;
  short8 af[8];

  // prologue: tile0 complete + tile1 ks0 (units 0..5); land tile0 (vmcnt(4))
  STAGE_(0,0,0); STAGE_(0,0,1); STAGE_(0,1,0); STAGE_(0,1,1);
  STAGE_(1,0,0); STAGE_(1,0,1);
  asm volatile("s_waitcnt vmcnt(4)" ::: "memory");
  __builtin_amdgcn_s_barrier();

// Merged phase: 12 reads; 2 stages; MFMA (compiler-interleaved fine lgkm
// waits); [vmcnt(4)]; fence+barrier. NO lgkm drain, NO sched_barrier.
#define CPH_(H, KS, STT, SKS, DOVM) do {                                    \
    const char* regA_ = ldsc + (H)*65536 + (KS)*16384;                      \
    const char* regB_ = regA_ + 32768;                                      \
    _Pragma("unroll")                                                       \
    for (int mi_ = 0; mi_ < 8; ++mi_)                                       \
      af[mi_] = *(const short8*)(regA_ + aoff + mi_*1024);                  \
    const short8 bb0_ = *(const short8*)(regB_ + boff);                     \
    const short8 bb1_ = *(const short8*)(regB_ + boff + 1024);              \
    const short8 bb2_ = *(const short8*)(regB_ + boff + 2048);              \
    const short8 bb3_ = *(const short8*)(regB_ + boff + 3072);              \
    STAGE_(t + (STT), SKS, 0);                                              \
    STAGE_(t + (STT), SKS, 1);                                              \
    __builtin_amdgcn_s_setprio(1);                                          \
    _Pragma("unroll")                                                       \
    for (int mi_ = 0; mi_ < 8; ++mi_) {                                     \
      acc[mi_][0] = mfma_bf16(af[mi_], bb0_, acc[mi_][0]);                  \
      acc[mi_][1] = mfma_bf16(af[mi_], bb1_, acc[mi_][1]);                  \
      acc[mi_][2] = mfma_bf16(af[mi_], bb2_, acc[mi_][2]);                  \
      acc[mi_][3] = mfma_bf16(af[mi_], bb3_, acc[mi_][3]);                  \
    }                                                                       \
    __builtin_amdgcn_s_setprio(0);                                          \
    if (DOVM) { asm volatile("s_waitcnt vmcnt(4)" ::: "memory"); }          \
    BARF();                                                                 \
  } while(0)

  const int niter = ntile >> 1;
  #pragma unroll 1
  for (int it = 0; it < niter; ++it) {
    const int t = it << 1;
    CPH_(0, 0, 1, 1, 0);   // reads tile t   ks0 | stages (t+1, ks1)
    CPH_(0, 1, 2, 0, 1);   // reads tile t   ks1 | stages (t+2, ks0) +vmcnt(4)
    CPH_(1, 0, 2, 1, 0);   // reads tile t+1 ks0 | stages (t+2, ks1)
    CPH_(1, 1, 3, 0, 1);   // reads tile t+1 ks1 | stages (t+3, ks0) +vmcnt(4)
  }
#undef CPH_
#undef STAGE_

  // ---- epilogue: drain trailing stages, then LDS-staged full-line stores ----
  asm volatile("s_waitcnt vmcnt(0)" ::: "memory");
  BARF();

  // C/D layout: col = lane&15, row = (lane>>4)*4 + reg  [m89-verified]
  const int lrow = lg << 2;
  if (EPI == 0){
    // bf16 gate tile 256x256: two row-half passes through [128][264] staging
    unsigned short* st = smem;
    #pragma unroll
    for (int p = 0; p < 2; ++p){                 // fully unrolled: p static
      if (wr == p){
        #pragma unroll
        for (int ni = 0; ni < 4; ++ni){
          const int col = wc*64 + ni*16 + l15;
          const int gcol = n0 + col;
          const float ib = bias[gcol], cf = coef[gcol], cb = convb[gcol];
          #pragma unroll
          for (int mi = 0; mi < 8; ++mi){
            const int rl = mi*16 + lrow;
            #pragma unroll
            for (int r = 0; r < 4; ++r){
              float z = (acc[mi][ni][r] + ib) * cf + cb;
              float g = z / (1.f + __expf(-z));       // silu
              st[(rl + r)*264 + col] = f32_to_bf16(g);
            }
          }
        }
      }
      BARF();
      #pragma unroll
      for (int rd = 0; rd < 8; ++rd){
        const int idx = rd*512 + tid;
        const int row = idx >> 5, c8 = (idx & 31) << 3;
        short8 v = *(const short8*)&st[row*264 + c8];
        *(short8*)&gate[(size_t)(m0 + p*128 + row) * N + n0 + c8] = v;
      }
      BARF();
    }
  } else {
    // f32 out tile 256x256: four 64-row passes through [64][260] staging
    float* stf = (float*)smem;
    #pragma unroll
    for (int p = 0; p < 4; ++p){                 // fully unrolled: p static,
      if (wr == (p >> 1)){                       // acc indices compile-time
        #pragma unroll
        for (int ni = 0; ni < 4; ++ni){
          const int col = wc*64 + ni*16 + l15;
          const float ob = bias[n0 + col];
          #pragma unroll
          for (int mi2 = 0; mi2 < 4; ++mi2){
            const int mi = (p & 1)*4 + mi2;      // compile-time
            const int rl = mi2*16 + lrow;
            #pragma unroll
            for (int r = 0; r < 4; ++r)
              stf[(rl + r)*260 + col] = acc[mi][ni][r] + ob;
          }
        }
      }
      BARF();
      #pragma unroll
      for (int rd = 0; rd < 8; ++rd){
        const int idx = rd*512 + tid;
        const int row = idx >> 6, c4 = (idx & 63) << 2;
        f32x4 v = *(const f32x4*)&stf[row*260 + c4];
        *(f32x4*)&out[(size_t)(m0 + p*64 + row) * N + n0 + c4] = v;
      }
      BARF();
    }
  }
}

// ---------------------------------------------------------------------------
// Fallback 128^2 GEMM, used only when ws can't hold bf16-converted x.
// ---------------------------------------------------------------------------
#define BM 128
#define BN 128
#define BK 64

__global__ __launch_bounds__(256) void gemm_bt_f32a_k(
    const float* __restrict__ A32, const unsigned short* __restrict__ Bt,
    int M, int N, int K,
    const float* __restrict__ bias,
    const float* __restrict__ coef,
    const float* __restrict__ convb,
    unsigned short* __restrict__ gate)
{
  __shared__ __align__(16) unsigned short lsA[BM*BK];
  __shared__ __align__(16) unsigned short lsB[BN*BK];
  const int tid = threadIdx.x;
  const int wid = tid >> 6, lane = tid & 63;
  const int wr = wid >> 1, wc = wid & 1;
  const int nbx = N / BN;
  const int cpx = gridDim.x >> 3;
  const int bid = blockIdx.x;
  const int swz = (bid & 7) * cpx + (bid >> 3);
  const int m0 = (swz / nbx) * BM, n0 = (swz % nbx) * BN;

  f32x4 acc[4][4];
  #pragma unroll
  for (int i = 0; i < 4; i++)
    #pragma unroll
    for (int j = 0; j < 4; j++)
      #pragma unroll
      for (int r = 0; r < 4; r++) acc[i][j][r] = 0.f;

  for (int kt = 0; kt < K; kt += BK){
    __syncthreads();
    #pragma unroll
    for (int i = 0; i < 8; i++){
      int c = tid + i*256;
      int row = c >> 4, c4 = (c & 15) << 2;
      const float4 v = *(const float4*)&A32[(size_t)(m0+row)*K + kt + c4];
      ushort4 o;
      o.x = f32_to_bf16(v.x); o.y = f32_to_bf16(v.y);
      o.z = f32_to_bf16(v.z); o.w = f32_to_bf16(v.w);
      *(ushort4*)&lsA[row*BK + c4] = o;
    }
    #pragma unroll
    for (int i = 0; i < 4; i++){
      int c = (wid*4 + i)*64 + lane;
      int row = c >> 3, c8 = (c & 7) << 3;
      gload_lds16(&Bt[(size_t)(n0+row)*K + kt + c8], &lsB[c*8]);
    }
    __syncthreads();

    #pragma unroll
    for (int ks = 0; ks < 2; ks++){
      short8 af[4], bf[4];
      const int ko = ks*32 + ((lane >> 4) << 3);
      #pragma unroll
      for (int mi = 0; mi < 4; mi++)
        af[mi] = *(const short8*)&lsA[(wr*64 + mi*16 + (lane & 15))*BK + ko];
      #pragma unroll
      for (int ni = 0; ni < 4; ni++)
        bf[ni] = *(const short8*)&lsB[(wc*64 + ni*16 + (lane & 15))*BK + ko];
      #pragma unroll
      for (int mi = 0; mi < 4; mi++)
        #pragma unroll
        for (int ni = 0; ni < 4; ni++)
          acc[mi][ni] = mfma_bf16(af[mi], bf[ni], acc[mi][ni]);
    }
  }

  const int lrow = (lane >> 4) << 2;
  const int lcol = lane & 15;
  #pragma unroll
  for (int ni = 0; ni < 4; ni++){
    int col = n0 + wc*64 + ni*16 + lcol;
    float ib = bias[col], cf = coef[col], cb = convb[col];
    #pragma unroll
    for (int mi = 0; mi < 4; mi++){
      int rb = m0 + wr*64 + mi*16 + lrow;
      #pragma unroll
      for (int r = 0; r < 4; r++){
        float z = (acc[mi][ni][r] + ib) * cf + cb;
        float g = z / (1.f + __expf(-z));
        gate[(size_t)(rb + r) * N + col] = f32_to_bf16(g);
      }
    }
  }
}

extern "C" void kernel_launch(void* const* d_in, const int* in_sizes, int n_in,
                              void* d_out, int out_size, void* d_ws, size_t ws_size,
                              hipStream_t stream){
  const float* x      = (const float*)d_in[0];
  const float* in_w   = (const float*)d_in[1];
  const float* in_b   = (const float*)d_in[2];
  const float* conv_w = (const float*)d_in[3];
  const float* conv_b = (const float*)d_in[4];
  // d_in[5] = A_log: cancels against h0=0, unused
  const float* Bm     = (const float*)d_in[6];
  const float* Cm     = (const float*)d_in[7];
  const float* Dp     = (const float*)d_in[8];
  const float* dt     = (const float*)d_in[9];
  const float* out_w  = (const float*)d_in[10];
  const float* out_b  = (const float*)d_in[11];

  const int M = in_sizes[0] / D_MODEL;   // 32768

  char* ws = (char*)d_ws;
  const size_t gate_sz = (size_t)M * D_INNER * 2;              // 256 MiB
  const size_t w1t_off = gate_sz;
  const size_t w1t_sz  = (size_t)D_MODEL * D_INNER * 2;        // 16 MiB
  const size_t w2t_off = w1t_off + w1t_sz;
  const size_t w2t_sz  = (size_t)D_INNER * D_MODEL * 2;        // 16 MiB
  const size_t coef_off = w2t_off + w2t_sz;
  const size_t coef_sz  = (size_t)D_INNER * 4;
  const size_t xb_off   = (coef_off + coef_sz + 255) & ~(size_t)255;
  const size_t xb_sz    = (size_t)M * D_MODEL * 2;             // 128 MiB

  unsigned short* gate = (unsigned short*)ws;
  unsigned short* w1t  = (unsigned short*)(ws + w1t_off);
  unsigned short* w2t  = (unsigned short*)(ws + w2t_off);
  float*          coef = (float*)(ws + coef_off);
  unsigned short* xb   = (unsigned short*)(ws + xb_off);
  const bool have_xb = ws_size >= xb_off + xb_sz;

  prep_coef_k<<<D_INNER/256, 256, 0, stream>>>(conv_w, Bm, Cm, Dp, dt, coef);
  transpose_cvt_k<<<dim3(D_INNER/32, D_MODEL/32), dim3(32,8), 0, stream>>>(in_w, w1t, D_MODEL, D_INNER);
  transpose_cvt_k<<<dim3(D_MODEL/32, D_INNER/32), dim3(32,8), 0, stream>>>(out_w, w2t, D_INNER, D_MODEL);
  if (have_xb)
    cvt_x_k<<<2048, 256, 0, stream>>>((const float4*)x, (ushort4*)xb, (M*D_MODEL)/4);

  if (have_xb){
    const int g1 = (M/256) * (D_INNER/256);   // 2048
    gemm8_k<0><<<g1, 512, 0, stream>>>(xb, w1t, M, D_INNER, D_MODEL,
                                       in_b, coef, conv_b, gate, nullptr);
  } else {
    const int g1 = (M/BM) * (D_INNER/BN);     // 8192
    gemm_bt_f32a_k<<<g1, 256, 0, stream>>>(x, w1t, M, D_INNER, D_MODEL,
                                           in_b, coef, conv_b, gate);
  }

  const int g2 = (M/256) * (D_MODEL/256);     // 1024
  gemm8_k<1><<<g2, 512, 0, stream>>>(gate, w2t, M, D_MODEL, D_INNER,
                                     out_b, nullptr, nullptr, nullptr, (float*)d_out);
}

// Round 9
// 1105.312 us; speedup vs baseline: 1.0621x; 1.0621x over previous
//
#include <hip/hip_runtime.h>
#include <stdint.h>
#include <stddef.h>

#define D_MODEL 2048
#define D_INNER 4096

typedef float f32x4 __attribute__((ext_vector_type(4)));
typedef short short8 __attribute__((ext_vector_type(8)));
typedef __bf16 bf16x8 __attribute__((ext_vector_type(8)));

static __device__ __forceinline__ unsigned short f32_to_bf16(float f){
  unsigned int u = __builtin_bit_cast(unsigned int, f);
  u += 0x7FFFu + ((u >> 16) & 1u);
  return (unsigned short)(u >> 16);
}

static __device__ __forceinline__ f32x4 mfma_bf16(short8 a, short8 b, f32x4 c){
  return __builtin_amdgcn_mfma_f32_16x16x32_bf16(
      __builtin_bit_cast(bf16x8, a), __builtin_bit_cast(bf16x8, b), c, 0, 0, 0);
}

static __device__ __forceinline__ void gload_lds16(const void* g, void* l){
  __builtin_amdgcn_global_load_lds(
      (const __attribute__((address_space(1))) void*)g,
      (__attribute__((address_space(3))) void*)l, 16, 0, 0);
}

// fenced barrier for epilogue (empty asm is codegen-free)
#define BARF() do { asm volatile("" ::: "memory"); \
                    __builtin_amdgcn_s_barrier();  \
                    asm volatile("" ::: "memory"); } while(0)

// coef[c] = conv_w[c,3] + softplus(dt[c]) * sum_n(B[c,n]*C[c,n]) + Dp[c]
__global__ void prep_coef_k(const float* __restrict__ conv_w, const float* __restrict__ Bm,
                            const float* __restrict__ Cm, const float* __restrict__ Dp,
                            const float* __restrict__ dt, float* __restrict__ coef){
  int c = blockIdx.x * 256 + threadIdx.x;
  if (c >= D_INNER) return;
  float d = dt[c];
  float sp = (d > 20.f) ? d : log1pf(__expf(d));
  float bc = 0.f;
  #pragma unroll
  for (int n = 0; n < 16; n++) bc += Bm[c*16+n] * Cm[c*16+n];
  coef[c] = conv_w[c*4+3] + sp * bc + Dp[c];
}

// in f32 [K][N] -> out bf16 [N][K]
__global__ void transpose_cvt_k(const float* __restrict__ in, unsigned short* __restrict__ outT,
                                int K, int N){
  __shared__ float t[32][33];
  int n0 = blockIdx.x * 32, k0 = blockIdx.y * 32;
  int tx = threadIdx.x, ty = threadIdx.y;
  #pragma unroll
  for (int i = 0; i < 4; i++)
    t[ty + 8*i][tx] = in[(size_t)(k0 + ty + 8*i) * N + n0 + tx];
  __syncthreads();
  #pragma unroll
  for (int i = 0; i < 4; i++)
    outT[(size_t)(n0 + ty + 8*i) * K + k0 + tx] = f32_to_bf16(t[tx][ty + 8*i]);
}

// x f32 -> bf16, vectorized (xb stays cached: it is re-read 16x by GEMM1)
__global__ void cvt_x_k(const float4* __restrict__ x, ushort4* __restrict__ xb, int n4){
  int stride = gridDim.x * blockDim.x;
  for (int i = blockIdx.x * blockDim.x + threadIdx.x; i < n4; i += stride){
    float4 v = x[i];
    ushort4 o;
    o.x = f32_to_bf16(v.x); o.y = f32_to_bf16(v.y);
    o.z = f32_to_bf16(v.z); o.w = f32_to_bf16(v.w);
    xb[i] = o;
  }
}

// ---------------------------------------------------------------------------
// 256x256 8-phase GEMM (round-6 structure = best measured, 585us/GEMM).
// C[M,N] = A[M,K]*Bt[N,K]^T, bf16 in, f32 accum.
// 512 thr = 8 waves (2M x 4N); per-wave 128x64 C. BK=64 in 2 K-halves.
// LDS: [slot:2][mat:2][ks:2][256 rows][32 k] bf16 = 128 KiB.
// Swizzle: 16B-chunk c' = c ^ ((row>>1)&3) -> conflict-free ds_read_b128.
// Block order: XCD-contiguous chunks, nb-fast (A re-reads L2-hit; B in L3).
// Phase: reads; stage; lgkm(0); sched_barrier; setprio(1); 16 MFMA;
// setprio(0); [vmcnt(4)@P4/P8]; barrier. (Single-barrier: round-6 +3.8%.)
// ROUND-9: output streams (gate / out) stored NON-TEMPORALLY. Diagnosis:
// 256 MiB of streaming writes per GEMM evicted the reused B-panels/A-source
// from L2/L3 -> FETCH 592 MB vs ~150 ideal (GEMM1, 4x over-fetch). The
// written streams are never re-read in the producing kernel -> nt is free.
// Epilogue: acc -> LDS (after vmcnt(0)) -> full-line nt dwordx4 stores.
// All epilogue acc indices compile-time (rule #20: runtime idx -> scratch).
// ---------------------------------------------------------------------------
template<int EPI>
__global__ __launch_bounds__(512, 2) void gemm8_k(
    const unsigned short* __restrict__ A,   // [M][K] bf16
    const unsigned short* __restrict__ Bt,  // [N][K] bf16
    int M, int N, int K,
    const float* __restrict__ bias,
    const float* __restrict__ coef,
    const float* __restrict__ convb,
    unsigned short* __restrict__ gate,
    float* __restrict__ out)
{
  __shared__ __align__(16) unsigned short smem[65536];   // 128 KiB
  char* ldsc = (char*)smem;

  const int tid = threadIdx.x;
  const int wid = tid >> 6, lane = tid & 63;
  const int wr = wid >> 2, wc = wid & 3;          // 2x4 wave grid
  const int l15 = lane & 15, lg = lane >> 4;

  const int nbx = N >> 8;
  const int cpx = gridDim.x >> 3;
  const int bid = blockIdx.x;
  const int swz = (bid & 7) * cpx + (bid >> 3);   // XCD-contiguous (nwg%8==0)
  const int mb = swz / nbx, nb = swz % nbx;       // nb-fast within XCD chunk
  const int m0 = mb << 8, n0 = nb << 8;

  // compute-side ds_read offsets (bytes within a 16 KiB region)
  const int cswz = lg ^ ((l15 >> 1) & 3);
  const int aoff = (wr*128 + l15)*64 + cswz*16;
  const int boff = (wc*64  + l15)*64 + cswz*16;

  // stage-side mapping: 2 instrs/thread, linear LDS dest, pre-swizzled source
  const int s0 = wid*128 + lane;
  const int s1 = s0 + 64;
  const int r0 = s0 >> 2, r1 = s1 >> 2;
  const int c0 = (s0 & 3) ^ ((r0 >> 1) & 3);
  const int c1 = (s1 & 3) ^ ((r1 >> 1) & 3);
  const unsigned short* pA0 = A  + (size_t)(m0 + r0)*K + c0*8;
  const unsigned short* pA1 = A  + (size_t)(m0 + r1)*K + c1*8;
  const unsigned short* pB0 = Bt + (size_t)(n0 + r0)*K + c0*8;
  const unsigned short* pB1 = Bt + (size_t)(n0 + r1)*K + c1*8;

  const int ntile = K >> 6;

#define STAGE_(ST, SKS, SMAT) do {                                          \
    int st_ = (ST); if (st_ > ntile-1) st_ = ntile-1;                       \
    const int ktks_ = st_*64 + (SKS)*32;                                    \
    unsigned short* reg_ = smem + ((st_ & 1) << 15) + ((SMAT) << 14) + ((SKS) << 13); \
    if ((SMAT) == 0) {                                                      \
      gload_lds16(pA0 + ktks_, reg_ + s0*8);                                \
      gload_lds16(pA1 + ktks_, reg_ + s1*8);                                \
    } else {                                                                \
      gload_lds16(pB0 + ktks_, reg_ + s0*8);                                \
      gload_lds16(pB1 + ktks_, reg_ + s1*8);                                \
    }                                                                       \
  } while(0)

  f32x4 acc[8][4];
  #pragma unroll
  for (int i = 0; i < 8; i++)
    #pragma unroll
    for (int j = 0; j < 4; j++)
      #pragma unroll
      for (int r = 0; r < 4; r++) acc[i][j][r] = 0.f;
  short8 af[8];

  // prologue: tile0 complete + tile1 ks0; land tile0 (vmcnt(4))
  STAGE_(0,0,0); STAGE_(0,0,1); STAGE_(0,1,0); STAGE_(0,1,1);
  STAGE_(1,0,0); STAGE_(1,0,1);
  asm volatile("s_waitcnt vmcnt(4)" ::: "memory");
  __builtin_amdgcn_s_barrier();

// Single-barrier phase: reads; stage; lgkm(0); pin; MFMA; [vmcnt(4)]; barrier
#define CPHASE_(H, KS, NP, SMAT, SKS, TADD, DOVM) do {                      \
    const char* regA_ = ldsc + (H)*65536 + (KS)*16384;                      \
    const char* regB_ = regA_ + 32768;                                      \
    if ((NP) == 0) {                                                        \
      _Pragma("unroll")                                                     \
      for (int mi_ = 0; mi_ < 8; ++mi_)                                     \
        af[mi_] = *(const short8*)(regA_ + aoff + mi_*1024);                \
    }                                                                       \
    const short8 b0_ = *(const short8*)(regB_ + boff + (NP)*2048);          \
    const short8 b1_ = *(const short8*)(regB_ + boff + (NP)*2048 + 1024);   \
    STAGE_(t + (TADD) + (H), SKS, SMAT);                                    \
    asm volatile("s_waitcnt lgkmcnt(0)" ::: "memory");                      \
    __builtin_amdgcn_sched_barrier(0);                                      \
    __builtin_amdgcn_s_setprio(1);                                          \
    _Pragma("unroll")                                                       \
    for (int mi_ = 0; mi_ < 8; ++mi_) {                                     \
      acc[mi_][(NP)*2]   = mfma_bf16(af[mi_], b0_, acc[mi_][(NP)*2]);       \
      acc[mi_][(NP)*2+1] = mfma_bf16(af[mi_], b1_, acc[mi_][(NP)*2+1]);     \
    }                                                                       \
    __builtin_amdgcn_s_setprio(0);                                          \
    if (DOVM) { asm volatile("s_waitcnt vmcnt(4)" ::: "memory"); }          \
    __builtin_amdgcn_s_barrier();                                           \
  } while(0)

  const int niter = ntile >> 1;
  #pragma unroll 1
  for (int it = 0; it < niter; ++it) {
    const int t = it << 1;
    CPHASE_(0, 0, 0, 0, 1, 1, 0);   // P1
    CPHASE_(0, 0, 1, 1, 1, 1, 0);   // P2
    CPHASE_(0, 1, 0, 0, 0, 2, 0);   // P3
    CPHASE_(0, 1, 1, 1, 0, 2, 1);   // P4 +vmcnt(4)
    CPHASE_(1, 0, 0, 0, 1, 1, 0);   // P5
    CPHASE_(1, 0, 1, 1, 1, 1, 0);   // P6
    CPHASE_(1, 1, 0, 0, 0, 2, 0);   // P7
    CPHASE_(1, 1, 1, 1, 0, 2, 1);   // P8 +vmcnt(4)
  }
#undef CPHASE_
#undef STAGE_

  // ---- epilogue: drain trailing stages, then LDS-staged full-line stores ----
  asm volatile("s_waitcnt vmcnt(0)" ::: "memory");
  BARF();

  // C/D layout: col = lane&15, row = (lane>>4)*4 + reg  [m89-verified]
  const int lrow = lg << 2;
  if (EPI == 0){
    // bf16 gate tile 256x256: two row-half passes through [128][264] staging
    unsigned short* st = smem;
    #pragma unroll
    for (int p = 0; p < 2; ++p){                 // fully unrolled: p static
      if (wr == p){
        #pragma unroll
        for (int ni = 0; ni < 4; ++ni){
          const int col = wc*64 + ni*16 + l15;
          const int gcol = n0 + col;
          const float ib = bias[gcol], cf = coef[gcol], cb = convb[gcol];
          #pragma unroll
          for (int mi = 0; mi < 8; ++mi){
            const int rl = mi*16 + lrow;
            #pragma unroll
            for (int r = 0; r < 4; ++r){
              float z = (acc[mi][ni][r] + ib) * cf + cb;
              float g = z / (1.f + __expf(-z));       // silu
              st[(rl + r)*264 + col] = f32_to_bf16(g);
            }
          }
        }
      }
      BARF();
      #pragma unroll
      for (int rd = 0; rd < 8; ++rd){
        const int idx = rd*512 + tid;
        const int row = idx >> 5, c8 = (idx & 31) << 3;
        short8 v = *(const short8*)&st[row*264 + c8];
        __builtin_nontemporal_store(
            v, (short8*)&gate[(size_t)(m0 + p*128 + row) * N + n0 + c8]);
      }
      BARF();
    }
  } else {
    // f32 out tile 256x256: four 64-row passes through [64][260] staging
    float* stf = (float*)smem;
    #pragma unroll
    for (int p = 0; p < 4; ++p){                 // fully unrolled: p static,
      if (wr == (p >> 1)){                       // acc indices compile-time
        #pragma unroll
        for (int ni = 0; ni < 4; ++ni){
          const int col = wc*64 + ni*16 + l15;
          const float ob = bias[n0 + col];
          #pragma unroll
          for (int mi2 = 0; mi2 < 4; ++mi2){
            const int mi = (p & 1)*4 + mi2;      // compile-time
            const int rl = mi2*16 + lrow;
            #pragma unroll
            for (int r = 0; r < 4; ++r)
              stf[(rl + r)*260 + col] = acc[mi][ni][r] + ob;
          }
        }
      }
      BARF();
      #pragma unroll
      for (int rd = 0; rd < 8; ++rd){
        const int idx = rd*512 + tid;
        const int row = idx >> 6, c4 = (idx & 63) << 2;
        f32x4 v = *(const f32x4*)&stf[row*260 + c4];
        __builtin_nontemporal_store(
            v, (f32x4*)&out[(size_t)(m0 + p*64 + row) * N + n0 + c4]);
      }
      BARF();
    }
  }
}

// ---------------------------------------------------------------------------
// Fallback 128^2 GEMM, used only when ws can't hold bf16-converted x.
// ---------------------------------------------------------------------------
#define BM 128
#define BN 128
#define BK 64

__global__ __launch_bounds__(256) void gemm_bt_f32a_k(
    const float* __restrict__ A32, const unsigned short* __restrict__ Bt,
    int M, int N, int K,
    const float* __restrict__ bias,
    const float* __restrict__ coef,
    const float* __restrict__ convb,
    unsigned short* __restrict__ gate)
{
  __shared__ __align__(16) unsigned short lsA[BM*BK];
  __shared__ __align__(16) unsigned short lsB[BN*BK];
  const int tid = threadIdx.x;
  const int wid = tid >> 6, lane = tid & 63;
  const int wr = wid >> 1, wc = wid & 1;
  const int nbx = N / BN;
  const int cpx = gridDim.x >> 3;
  const int bid = blockIdx.x;
  const int swz = (bid & 7) * cpx + (bid >> 3);
  const int m0 = (swz / nbx) * BM, n0 = (swz % nbx) * BN;

  f32x4 acc[4][4];
  #pragma unroll
  for (int i = 0; i < 4; i++)
    #pragma unroll
    for (int j = 0; j < 4; j++)
      #pragma unroll
      for (int r = 0; r < 4; r++) acc[i][j][r] = 0.f;

  for (int kt = 0; kt < K; kt += BK){
    __syncthreads();
    #pragma unroll
    for (int i = 0; i < 8; i++){
      int c = tid + i*256;
      int row = c >> 4, c4 = (c & 15) << 2;
      const float4 v = *(const float4*)&A32[(size_t)(m0+row)*K + kt + c4];
      ushort4 o;
      o.x = f32_to_bf16(v.x); o.y = f32_to_bf16(v.y);
      o.z = f32_to_bf16(v.z); o.w = f32_to_bf16(v.w);
      *(ushort4*)&lsA[row*BK + c4] = o;
    }
    #pragma unroll
    for (int i = 0; i < 4; i++){
      int c = (wid*4 + i)*64 + lane;
      int row = c >> 3, c8 = (c & 7) << 3;
      gload_lds16(&Bt[(size_t)(n0+row)*K + kt + c8], &lsB[c*8]);
    }
    __syncthreads();

    #pragma unroll
    for (int ks = 0; ks < 2; ks++){
      short8 af[4], bf[4];
      const int ko = ks*32 + ((lane >> 4) << 3);
      #pragma unroll
      for (int mi = 0; mi < 4; mi++)
        af[mi] = *(const short8*)&lsA[(wr*64 + mi*16 + (lane & 15))*BK + ko];
      #pragma unroll
      for (int ni = 0; ni < 4; ni++)
        bf[ni] = *(const short8*)&lsB[(wc*64 + ni*16 + (lane & 15))*BK + ko];
      #pragma unroll
      for (int mi = 0; mi < 4; mi++)
        #pragma unroll
        for (int ni = 0; ni < 4; ni++)
          acc[mi][ni] = mfma_bf16(af[mi], bf[ni], acc[mi][ni]);
    }
  }

  const int lrow = (lane >> 4) << 2;
  const int lcol = lane & 15;
  #pragma unroll
  for (int ni = 0; ni < 4; ni++){
    int col = n0 + wc*64 + ni*16 + lcol;
    float ib = bias[col], cf = coef[col], cb = convb[col];
    #pragma unroll
    for (int mi = 0; mi < 4; mi++){
      int rb = m0 + wr*64 + mi*16 + lrow;
      #pragma unroll
      for (int r = 0; r < 4; r++){
        float z = (acc[mi][ni][r] + ib) * cf + cb;
        float g = z / (1.f + __expf(-z));
        gate[(size_t)(rb + r) * N + col] = f32_to_bf16(g);
      }
    }
  }
}

extern "C" void kernel_launch(void* const* d_in, const int* in_sizes, int n_in,
                              void* d_out, int out_size, void* d_ws, size_t ws_size,
                              hipStream_t stream){
  const float* x      = (const float*)d_in[0];
  const float* in_w   = (const float*)d_in[1];
  const float* in_b   = (const float*)d_in[2];
  const float* conv_w = (const float*)d_in[3];
  const float* conv_b = (const float*)d_in[4];
  // d_in[5] = A_log: cancels against h0=0, unused
  const float* Bm     = (const float*)d_in[6];
  const float* Cm     = (const float*)d_in[7];
  const float* Dp     = (const float*)d_in[8];
  const float* dt     = (const float*)d_in[9];
  const float* out_w  = (const float*)d_in[10];
  const float* out_b  = (const float*)d_in[11];

  const int M = in_sizes[0] / D_MODEL;   // 32768

  char* ws = (char*)d_ws;
  const size_t gate_sz = (size_t)M * D_INNER * 2;              // 256 MiB
  const size_t w1t_off = gate_sz;
  const size_t w1t_sz  = (size_t)D_MODEL * D_INNER * 2;        // 16 MiB
  const size_t w2t_off = w1t_off + w1t_sz;
  const size_t w2t_sz  = (size_t)D_INNER * D_MODEL * 2;        // 16 MiB
  const size_t coef_off = w2t_off + w2t_sz;
  const size_t coef_sz  = (size_t)D_INNER * 4;
  const size_t xb_off   = (coef_off + coef_sz + 255) & ~(size_t)255;
  const size_t xb_sz    = (size_t)M * D_MODEL * 2;             // 128 MiB

  unsigned short* gate = (unsigned short*)ws;
  unsigned short* w1t  = (unsigned short*)(ws + w1t_off);
  unsigned short* w2t  = (unsigned short*)(ws + w2t_off);
  float*          coef = (float*)(ws + coef_off);
  unsigned short* xb   = (unsigned short*)(ws + xb_off);
  const bool have_xb = ws_size >= xb_off + xb_sz;

  prep_coef_k<<<D_INNER/256, 256, 0, stream>>>(conv_w, Bm, Cm, Dp, dt, coef);
  transpose_cvt_k<<<dim3(D_INNER/32, D_MODEL/32), dim3(32,8), 0, stream>>>(in_w, w1t, D_MODEL, D_INNER);
  transpose_cvt_k<<<dim3(D_MODEL/32, D_INNER/32), dim3(32,8), 0, stream>>>(out_w, w2t, D_INNER, D_MODEL);
  if (have_xb)
    cvt_x_k<<<2048, 256, 0, stream>>>((const float4*)x, (ushort4*)xb, (M*D_MODEL)/4);

  if (have_xb){
    const int g1 = (M/256) * (D_INNER/256);   // 2048
    gemm8_k<0><<<g1, 512, 0, stream>>>(xb, w1t, M, D_INNER, D_MODEL,
                                       in_b, coef, conv_b, gate, nullptr);
  } else {
    const int g1 = (M/BM) * (D_INNER/BN);     // 8192
    gemm_bt_f32a_k<<<g1, 256, 0, stream>>>(x, w1t, M, D_INNER, D_MODEL,
                                           in_b, coef, conv_b, gate);
  }

  const int g2 = (M/256) * (D_MODEL/256);     // 1024
  gemm8_k<1><<<g2, 512, 0, stream>>>(gate, w2t, M, D_MODEL, D_INNER,
                                     out_b, nullptr, nullptr, nullptr, (float*)d_out);
}